// Round 8
// baseline (306.934 us; speedup 1.0000x reference)
//
#include <hip/hip_runtime.h>

// DynamicExpertGating: routed MoE on MI355X (gfx950)
//   tokens T=8192 (B4 x S2048), H=1024, D=1024, E=8, top-2
// R12: expert_gemm is LDS-READ-THROUGHPUT-BOUND (per-CU: 16 blk x 32 step
//   x 4 waves x 8 ds_read_b128 x ~12cyc = 196k cyc vs 201k total = 98%).
//   Fix: A operand global->register direct (double-buffered, 1-step
//   prefetch; same 64B/row L2 segments as the old gather), B keeps the
//   proven 3-buf gld_lds counted-vmcnt path. LDS reads halve -> ~41us
//   floor. vmcnt accounting includes A reg-loads: steady newer-than-B(kk)
//   = A(kk+1)4 + B(kk+2)2 = 6 -> vmcnt(6); prologue ordered B0,A0,B1 so
//   kk=0 count matches; kk=31 -> vmcnt(4).
//   Back half: fused out_gemm REVERTED (drain-0 loop cost ~+19us);
//   R8 combine + counted out_gemm restored. pre_kernel fusion kept.
//
// ws layout (bytes):
//   [0,16M)   x_bf16 [8192][1024] (reused as combined bf16 later)
//   [16M,32M) weT [8][1024 d][1024 h] bf16 ; [32M,34M) woT bf16
//   [34M,66M) outE [16384 packed rows][1024] bf16
//   [66M+..]  counts[8], tok2[8][8192], wlist[8][8192], eidx[16384],
//             ew[16384] (reused as s2p[16384] after build_lists)

#define TOKENS 8192
#define HDIM   1024
#define DDIM   1024
#define NEXP   8

typedef __bf16 bf16x8 __attribute__((ext_vector_type(8)));
typedef float  f32x4  __attribute__((ext_vector_type(4)));

__device__ __forceinline__ unsigned short f2b(float f) {
  unsigned int u = __builtin_bit_cast(unsigned int, f);
  u = u + 0x7fffu + ((u >> 16) & 1u);   // round-to-nearest-even
  return (unsigned short)(u >> 16);
}
__device__ __forceinline__ float b2f(unsigned short b) {
  unsigned int u = ((unsigned int)b) << 16;
  return __builtin_bit_cast(float, u);
}

__device__ __forceinline__ void gld_lds16(const void* g, void* l) {
  __builtin_amdgcn_global_load_lds(
      (__attribute__((address_space(1))) void*)(g),
      (__attribute__((address_space(3))) void*)(l),
      16, 0, 0);
}

// ---------------- fused pre-kernel (router + weight transpose) -------------
// blocks [0, 2048):         router (4 tokens/block, 4 waves) -> eidx/ew/xb
// blocks [2048, 2048+9216): transpose+convert (we slices 0..7, wo 8)

__global__ __launch_bounds__(256) void pre_kernel(
    const float* __restrict__ x, const float* __restrict__ wr,
    const float* __restrict__ br,
    const float* __restrict__ we, const float* __restrict__ wo,
    unsigned short* __restrict__ weT, unsigned short* __restrict__ woT,
    unsigned short* __restrict__ xb,
    int* __restrict__ eidx, float* __restrict__ ew) {
  __shared__ unsigned short tile[32][33];
  int tid = threadIdx.x;
  if (blockIdx.x >= 2048) {
    int lid = blockIdx.x - 2048;
    int z = lid >> 10;                 // 9 slices
    int rem = lid & 1023;
    int bx = (rem & 31) * 32;          // src col / dst row
    int by = (rem >> 5) * 32;          // src row / dst col
    const float* s;
    unsigned short* d;
    if (z < 8) { s = we + (size_t)z * HDIM * DDIM; d = weT + (size_t)z * HDIM * DDIM; }
    else       { s = wo;                            d = woT; }
    int tx = tid & 31, ty = tid >> 5;  // 32 x 8
    for (int i = ty; i < 32; i += 8)
      tile[i][tx] = f2b(s[(size_t)(by + i) * 1024 + bx + tx]);
    __syncthreads();
    for (int i = ty; i < 32; i += 8)
      d[(size_t)(bx + i) * 1024 + by + tx] = tile[tx][i];
    return;
  }
  // ---- router branch (no atomics; compaction happens in build_lists) ----
  int wave = tid >> 6, lane = tid & 63;
  int t = blockIdx.x * 4 + wave;
  const float* xp = x + (size_t)t * HDIM;
  unsigned short* xbp = xb + (size_t)t * HDIM;
  float acc[8];
#pragma unroll
  for (int e = 0; e < 8; ++e) acc[e] = 0.f;
#pragma unroll
  for (int h0 = 0; h0 < HDIM; h0 += 256) {
    int h = h0 + lane * 4;
    float4 xv = *(const float4*)&xp[h];
    ushort4 o;
    o.x = f2b(xv.x); o.y = f2b(xv.y); o.z = f2b(xv.z); o.w = f2b(xv.w);
    *(ushort4*)&xbp[h] = o;
    float xq[4] = {xv.x, xv.y, xv.z, xv.w};
#pragma unroll
    for (int q = 0; q < 4; ++q) {
      const float4* wp = (const float4*)&wr[(h + q) * 8];
      float4 w0 = wp[0], w1 = wp[1];
      acc[0] += xq[q] * w0.x; acc[1] += xq[q] * w0.y; acc[2] += xq[q] * w0.z; acc[3] += xq[q] * w0.w;
      acc[4] += xq[q] * w1.x; acc[5] += xq[q] * w1.y; acc[6] += xq[q] * w1.z; acc[7] += xq[q] * w1.w;
    }
  }
#pragma unroll
  for (int off = 32; off; off >>= 1)
#pragma unroll
    for (int e = 0; e < 8; ++e) acc[e] += __shfl_xor(acc[e], off, 64);
  if (lane == 0) {
    float l[8], p[8];
    float m = -1e30f;
#pragma unroll
    for (int e = 0; e < 8; ++e) { l[e] = acc[e] + br[e]; m = fmaxf(m, l[e]); }
    float s = 0.f;
#pragma unroll
    for (int e = 0; e < 8; ++e) { p[e] = __expf(l[e] - m); s += p[e]; }
    int i1 = 0;
#pragma unroll
    for (int e = 1; e < 8; ++e) if (p[e] > p[i1]) i1 = e;   // ties -> lower idx
    int i2 = (i1 == 0) ? 1 : 0;
#pragma unroll
    for (int e = 0; e < 8; ++e) if (e != i1 && p[e] > p[i2]) i2 = e;
    float ps = p[i1] + p[i2];
    eidx[t * 2]     = i1;  ew[t * 2]     = p[i1] / ps;
    eidx[t * 2 + 1] = i2;  ew[t * 2 + 1] = p[i2] / ps;
  }
}

// ---------------- router pass 2: per-expert stream compaction --------------

__global__ __launch_bounds__(1024) void build_lists_kernel(
    const int* __restrict__ eidx, const float* ew,
    int* __restrict__ counts, int* __restrict__ tok2, float* __restrict__ wl,
    int* s2p) {
  int e = blockIdx.x;
  int tid = threadIdx.x;
  int lane = tid & 63, wv = tid >> 6;    // 16 waves
  __shared__ int wsum[16];
  __shared__ int base;
  if (tid == 0) base = 0;
  __syncthreads();
  for (int c = 0; c < 2 * TOKENS; c += 1024) {
    int i = c + tid;
    bool m = (eidx[i] == e);
    unsigned long long bal = __ballot(m);
    if (lane == 0) wsum[wv] = __popcll(bal);
    __syncthreads();
    int wbase = base;
    for (int w = 0; w < wv; ++w) wbase += wsum[w];
    if (m) {
      int pos = wbase + __popcll(bal & ((1ull << lane) - 1ull));
      float w = ew[i];                     // read BEFORE aliased write
      tok2[e * TOKENS + pos] = i;          // i = token*2 + slot
      wl[e * TOKENS + pos] = w;
      s2p[i] = pos;
    }
    int total = 0;
#pragma unroll
    for (int w = 0; w < 16; ++w) total += wsum[w];
    __syncthreads();
    if (tid == 0) base += total;
    __syncthreads();
  }
  if (tid == 0) counts[e] = base;
}

// ---------------- gathered expert GEMM + gelu*gate epilogue ----------------
// 128x128 tile, BK=32, 4 waves 2x2. A: global->reg direct (dbuf, 1-step
// prefetch). B: 3-buffer gld_lds, counted vmcnt(6). XCD swizzle.

__global__ __launch_bounds__(256, 3) void expert_gemm_kernel(
    const unsigned short* __restrict__ xb, const unsigned short* __restrict__ weT,
    const float* __restrict__ b_experts, const int* __restrict__ counts,
    const int* __restrict__ tok2, const float* __restrict__ wlist,
    unsigned short* __restrict__ outE) {
  int b = blockIdx.x;
  int id = (b >> 3) + (b & 7) * 512;      // XCD k <- expert k's 512 tiles
  int e = id >> 9;
  int rem = id & 511;
  int m0 = (rem >> 3) << 7;
  int n0 = (rem & 7) << 7;
  int cnt = counts[e];
  if (m0 >= cnt) return;
  int cbase = 0;
  for (int q = 0; q < e; ++q) cbase += counts[q];

  __shared__ unsigned short Bs[3][128 * 32];   // 24KB: B only
  __shared__ int   tokS[128];
  __shared__ float wS[128];

  int tid = threadIdx.x;
  if (tid < 128) {
    int r = m0 + tid;
    tokS[tid] = (r < cnt) ? tok2[e * TOKENS + r] : 0;
    wS[tid]   = (r < cnt) ? wlist[e * TOKENS + r] : 0.f;
  }
  __syncthreads();

  int wave = tid >> 6, lane = tid & 63;
  int subr = lane >> 2, koff = (lane & 3) * 8;

  const unsigned short* wbase = weT + (size_t)e * (HDIM * DDIM);
  const unsigned short* bsrc[2];
  unsigned short* bdst[3][2];
#pragma unroll
  for (int i = 0; i < 2; ++i) {
    int row = i * 64 + wave * 16 + subr;
    bsrc[i] = wbase + (size_t)(n0 + row) * HDIM + koff;
#pragma unroll
    for (int bb = 0; bb < 3; ++bb)
      bdst[bb][i] = &Bs[bb][i * 2048 + wave * 512];
  }

  int wm = wave & 1, wn = wave >> 1;
  int quad = lane >> 4, lr = lane & 15;

  // A-direct per-lane pointers: 4 fragment rows (i*16), 16B at quad*8
  const unsigned short* aptr[4];
#pragma unroll
  for (int i = 0; i < 4; ++i)
    aptr[i] = xb + (size_t)(tokS[wm * 64 + i * 16 + lr] >> 1) * HDIM + quad * 8;

  f32x4 zero = {0.f, 0.f, 0.f, 0.f};
  f32x4 acc[4][4];
#pragma unroll
  for (int i = 0; i < 4; ++i)
#pragma unroll
    for (int j = 0; j < 4; ++j) acc[i][j] = zero;

  bf16x8 areg[2][4];
  // prologue, order pinned: B(0) gld_lds, A(0) regs, B(1) gld_lds
#pragma unroll
  for (int i = 0; i < 2; ++i) gld_lds16(bsrc[i], bdst[0][i]);
  asm volatile("" ::: "memory");
#pragma unroll
  for (int i = 0; i < 4; ++i) areg[0][i] = *(const bf16x8*)(aptr[i]);
  asm volatile("" ::: "memory");
#pragma unroll
  for (int i = 0; i < 2; ++i) gld_lds16(bsrc[i] + 32, bdst[1][i]);

#pragma unroll
  for (int kk = 0; kk < 32; ++kk) {
    // B(kk) landed when newer ops (A(kk+1)x4 + B(kk+2)x2 = 6) remain.
    if (kk < 31) asm volatile("s_waitcnt vmcnt(6)" ::: "memory");
    else         asm volatile("s_waitcnt vmcnt(4)" ::: "memory");
    __builtin_amdgcn_s_barrier();        // all waves' B(kk) visible
    if (kk < 31) {
#pragma unroll
      for (int i = 0; i < 4; ++i)
        areg[(kk + 1) & 1][i] = *(const bf16x8*)(aptr[i] + (kk + 1) * 32);
    }
    if (kk + 2 < 32) {
#pragma unroll
      for (int i = 0; i < 2; ++i)
        gld_lds16(bsrc[i] + (kk + 2) * 32, bdst[(kk + 2) % 3][i]);
    }
    bf16x8 bfr[4];
#pragma unroll
    for (int j = 0; j < 4; ++j)
      bfr[j] = *(const bf16x8*)&Bs[kk % 3][(wn * 64 + j * 16 + lr) * 32 + quad * 8];
#pragma unroll
    for (int i = 0; i < 4; ++i)
#pragma unroll
      for (int j = 0; j < 4; ++j)
        acc[i][j] = __builtin_amdgcn_mfma_f32_16x16x32_bf16(areg[kk & 1][i], bfr[j], acc[i][j], 0, 0, 0);
  }

  // epilogue: dense stores into the packed window [cbase+m0, cbase+m0+128)
  int rowbase = cbase + m0;
#pragma unroll
  for (int j = 0; j < 4; ++j) {
    int col = n0 + wn * 64 + j * 16 + lr;
    float bias = b_experts[e * DDIM + col];
#pragma unroll
    for (int i = 0; i < 4; ++i) {
      int rbase = wm * 64 + i * 16 + quad * 4;
#pragma unroll
      for (int r = 0; r < 4; ++r) {
        int row = rbase + r;
        if (m0 + row < cnt) {
          float h = acc[i][j][r] + bias;
          float z = 0.7978845608f * (h + 0.044715f * h * h * h);
          float t = 1.f - 2.f / (__expf(2.f * z) + 1.f);
          float g = 0.5f * h * (1.f + t);
          outE[(size_t)(rowbase + row) * DDIM + col] = f2b(g * wS[row]);
        }
      }
    }
  }
}

// ---------------- combine the two slots -> bf16 combined ----------------

__global__ void combine_kernel(const ushort4* __restrict__ outE,
                               const int* __restrict__ eidx, const int* __restrict__ s2p,
                               const int* __restrict__ counts,
                               ushort4* __restrict__ comb) {
  __shared__ int cbase[8];
  int tid = threadIdx.x;
  if (tid < 8) {
    int s = 0;
    for (int q = 0; q < tid; ++q) s += counts[q];
    cbase[tid] = s;
  }
  __syncthreads();
  int t = blockIdx.x;
  int d4 = tid;                          // 256 threads cover 1024 shorts
  int i0 = t * 2, i1 = i0 + 1;
  size_t r0 = ((size_t)(cbase[eidx[i0]] + s2p[i0])) * 256 + d4;
  size_t r1 = ((size_t)(cbase[eidx[i1]] + s2p[i1])) * 256 + d4;
  ushort4 a = outE[r0];
  ushort4 b = outE[r1];
  ushort4 o;
  o.x = f2b(b2f(a.x) + b2f(b.x));
  o.y = f2b(b2f(a.y) + b2f(b.y));
  o.z = f2b(b2f(a.z) + b2f(b.z));
  o.w = f2b(b2f(a.w) + b2f(b.w));
  comb[t * 256 + d4] = o;
}

// ---------------- output projection GEMM (fp32 out) ----------------
// 128x128, 3-buffer counted-vmcnt pipeline, XCD swizzle (n-slab per XCD).

__global__ __launch_bounds__(256, 3) void out_gemm_kernel(
    const unsigned short* __restrict__ Abf, const unsigned short* __restrict__ BT,
    const float* __restrict__ bias, float* __restrict__ out) {
  int b = blockIdx.x;
  int id = (b >> 3) + (b & 7) * 64;       // XCD k <- n-tile k's 64 m-tiles
  int n0 = (id >> 6) << 7;
  int m0 = (id & 63) << 7;

  __shared__ unsigned short As[3][128 * 32];
  __shared__ unsigned short Bs[3][128 * 32];
  int tid = threadIdx.x, wave = tid >> 6, lane = tid & 63;
  int subr = lane >> 2, koff = (lane & 3) * 8;

  const unsigned short* asrc[2];
  const unsigned short* bsrc[2];
  unsigned short* adst[3][2];
  unsigned short* bdst[3][2];
#pragma unroll
  for (int i = 0; i < 2; ++i) {
    int row = i * 64 + wave * 16 + subr;
    asrc[i] = Abf + (size_t)(m0 + row) * DDIM + koff;
    bsrc[i] = BT + (size_t)(n0 + row) * DDIM + koff;
#pragma unroll
    for (int bb = 0; bb < 3; ++bb) {
      adst[bb][i] = &As[bb][i * 2048 + wave * 512];
      bdst[bb][i] = &Bs[bb][i * 2048 + wave * 512];
    }
  }

  int wm = wave & 1, wn = wave >> 1;
  int quad = lane >> 4, lr = lane & 15;

  f32x4 zero = {0.f, 0.f, 0.f, 0.f};
  f32x4 acc[4][4];
#pragma unroll
  for (int i = 0; i < 4; ++i)
#pragma unroll
    for (int j = 0; j < 4; ++j) acc[i][j] = zero;

#pragma unroll
  for (int s = 0; s < 2; ++s)
#pragma unroll
    for (int i = 0; i < 2; ++i) {
      gld_lds16(asrc[i] + s * 32, adst[s][i]);
      gld_lds16(bsrc[i] + s * 32, bdst[s][i]);
    }

#pragma unroll
  for (int kk = 0; kk < 32; ++kk) {
    if (kk < 31) asm volatile("s_waitcnt vmcnt(4)" ::: "memory");
    else         asm volatile("s_waitcnt vmcnt(0)" ::: "memory");
    __builtin_amdgcn_s_barrier();
    if (kk + 2 < 32) {
      int nb = (kk + 2) % 3;
      int off = (kk + 2) * 32;
#pragma unroll
      for (int i = 0; i < 2; ++i) {
        gld_lds16(asrc[i] + off, adst[nb][i]);
        gld_lds16(bsrc[i] + off, bdst[nb][i]);
      }
    }
    int cb = kk % 3;
    bf16x8 af[4], bfr[4];
#pragma unroll
    for (int i = 0; i < 4; ++i)
      af[i] = *(const bf16x8*)&As[cb][(wm * 64 + i * 16 + lr) * 32 + quad * 8];
#pragma unroll
    for (int j = 0; j < 4; ++j)
      bfr[j] = *(const bf16x8*)&Bs[cb][(wn * 64 + j * 16 + lr) * 32 + quad * 8];
#pragma unroll
    for (int i = 0; i < 4; ++i)
#pragma unroll
      for (int j = 0; j < 4; ++j)
        acc[i][j] = __builtin_amdgcn_mfma_f32_16x16x32_bf16(af[i], bfr[j], acc[i][j], 0, 0, 0);
  }

#pragma unroll
  for (int j = 0; j < 4; ++j) {
    int col = n0 + wn * 64 + j * 16 + lr;
    float bs = bias[col];
#pragma unroll
    for (int i = 0; i < 4; ++i) {
      int rbase = wm * 64 + i * 16 + quad * 4;
#pragma unroll
      for (int r = 0; r < 4; ++r)
        out[(size_t)(m0 + rbase + r) * DDIM + col] = acc[i][j][r] + bs;
    }
  }
}

// ---------------- launch ----------------

extern "C" void kernel_launch(void* const* d_in, const int* in_sizes, int n_in,
                              void* d_out, int out_size, void* d_ws, size_t ws_size,
                              hipStream_t stream) {
  const float* x  = (const float*)d_in[0];
  const float* wr = (const float*)d_in[1];
  const float* br = (const float*)d_in[2];
  const float* we = (const float*)d_in[3];
  const float* be = (const float*)d_in[4];
  const float* wo = (const float*)d_in[5];
  const float* bo = (const float*)d_in[6];
  float* out = (float*)d_out;

  char* ws = (char*)d_ws;
  unsigned short* xb      = (unsigned short*)(ws);                  // 16 MB
  unsigned short* weT     = (unsigned short*)(ws + 16777216);       // 16 MB
  unsigned short* woT     = (unsigned short*)(ws + 33554432);       //  2 MB
  unsigned short* outE    = (unsigned short*)(ws + 35651584);       // 32 MB
  int*            counts  = (int*)           (ws + 69206016);       // 256 B
  int*            tok2    = (int*)           (ws + 69206272);       // 256 KB
  float*          wlist   = (float*)         (ws + 69468416);       // 256 KB
  int*            eidx    = (int*)           (ws + 69730560);       // 64 KB
  float*          ew      = (float*)         (ws + 69796096);       // 64 KB
  int*            s2p     = (int*)ew;  // alias: ew dead after build_lists
  unsigned short* comb    = xb;        // alias: xb dead after expert_gemm

  pre_kernel<<<2048 + 9216, 256, 0, stream>>>(x, wr, br, we, wo, weT, woT,
                                              xb, eidx, ew);
  build_lists_kernel<<<8, 1024, 0, stream>>>(eidx, ew, counts, tok2, wlist, s2p);
  expert_gemm_kernel<<<4096, 256, 0, stream>>>(xb, weT, be, counts, tok2, wlist, outE);
  combine_kernel<<<8192, 256, 0, stream>>>((const ushort4*)outE, eidx, s2p, counts, (ushort4*)comb);
  out_gemm_kernel<<<512, 256, 0, stream>>>(comb, woT, bo, out);
}

// Round 9
// 260.702 us; speedup vs baseline: 1.1773x; 1.1773x over previous
//
#include <hip/hip_runtime.h>

// DynamicExpertGating: routed MoE on MI355X (gfx950)
//   tokens T=8192 (B4 x S2048), H=1024, D=1024, E=8, top-2
// R13: consolidation to best-measured config (R5 = 280.0us) + cheap wins.
//   - expert_gemm / combine / out_gemm: R5-exact (token-layout outslot,
//     128^2, 3-buffer counted-vmcnt). R12's reg-A refuted the LDS-
//     throughput theory (conflicts halved, time +37%) -> latency/structure
//     bound at ~410 TF, consistent with m97-family shape curve.
//   - pre_kernel fusion kept (router+transpose, one launch saved).
//   - build_lists v2: int4/float4 loads, 4 ballots per 4096-chunk in slot
//     order; barriers 48->12. List permutation is output-invariant
//     (outslot token-indexed; weights travel with tok2 entries).
//   Pipeline: pre -> build_lists -> expert_gemm -> combine -> out_gemm.
//
// ws layout (bytes):
//   [0,16M)   x_bf16 [8192][1024] (reused as combined bf16 later)
//   [16M,32M) weT [8][1024 d][1024 h] bf16 ; [32M,34M) woT bf16
//   [34M,66M) outslot [8192 tok][2 slot][1024] bf16
//   [66M+..]  counts[8], tok2[8][8192], wlist[8][8192], eidx[16384], ew[16384]

#define TOKENS 8192
#define HDIM   1024
#define DDIM   1024
#define NEXP   8

typedef __bf16 bf16x8 __attribute__((ext_vector_type(8)));
typedef float  f32x4  __attribute__((ext_vector_type(4)));

__device__ __forceinline__ unsigned short f2b(float f) {
  unsigned int u = __builtin_bit_cast(unsigned int, f);
  u = u + 0x7fffu + ((u >> 16) & 1u);   // round-to-nearest-even
  return (unsigned short)(u >> 16);
}
__device__ __forceinline__ float b2f(unsigned short b) {
  unsigned int u = ((unsigned int)b) << 16;
  return __builtin_bit_cast(float, u);
}

__device__ __forceinline__ void gld_lds16(const void* g, void* l) {
  __builtin_amdgcn_global_load_lds(
      (__attribute__((address_space(1))) void*)(g),
      (__attribute__((address_space(3))) void*)(l),
      16, 0, 0);
}

// ---------------- fused pre-kernel (router + weight transpose) -------------
// blocks [0, 2048):         router (4 tokens/block, 4 waves) -> eidx/ew/xb
// blocks [2048, 2048+9216): transpose+convert (we slices 0..7, wo 8)

__global__ __launch_bounds__(256) void pre_kernel(
    const float* __restrict__ x, const float* __restrict__ wr,
    const float* __restrict__ br,
    const float* __restrict__ we, const float* __restrict__ wo,
    unsigned short* __restrict__ weT, unsigned short* __restrict__ woT,
    unsigned short* __restrict__ xb,
    int* __restrict__ eidx, float* __restrict__ ew) {
  __shared__ unsigned short tile[32][33];
  int tid = threadIdx.x;
  if (blockIdx.x >= 2048) {
    int lid = blockIdx.x - 2048;
    int z = lid >> 10;                 // 9 slices
    int rem = lid & 1023;
    int bx = (rem & 31) * 32;          // src col / dst row
    int by = (rem >> 5) * 32;          // src row / dst col
    const float* s;
    unsigned short* d;
    if (z < 8) { s = we + (size_t)z * HDIM * DDIM; d = weT + (size_t)z * HDIM * DDIM; }
    else       { s = wo;                            d = woT; }
    int tx = tid & 31, ty = tid >> 5;  // 32 x 8
    for (int i = ty; i < 32; i += 8)
      tile[i][tx] = f2b(s[(size_t)(by + i) * 1024 + bx + tx]);
    __syncthreads();
    for (int i = ty; i < 32; i += 8)
      d[(size_t)(bx + i) * 1024 + by + tx] = tile[tx][i];
    return;
  }
  // ---- router branch (no atomics; compaction happens in build_lists) ----
  int wave = tid >> 6, lane = tid & 63;
  int t = blockIdx.x * 4 + wave;
  const float* xp = x + (size_t)t * HDIM;
  unsigned short* xbp = xb + (size_t)t * HDIM;
  float acc[8];
#pragma unroll
  for (int e = 0; e < 8; ++e) acc[e] = 0.f;
#pragma unroll
  for (int h0 = 0; h0 < HDIM; h0 += 256) {
    int h = h0 + lane * 4;
    float4 xv = *(const float4*)&xp[h];
    ushort4 o;
    o.x = f2b(xv.x); o.y = f2b(xv.y); o.z = f2b(xv.z); o.w = f2b(xv.w);
    *(ushort4*)&xbp[h] = o;
    float xq[4] = {xv.x, xv.y, xv.z, xv.w};
#pragma unroll
    for (int q = 0; q < 4; ++q) {
      const float4* wp = (const float4*)&wr[(h + q) * 8];
      float4 w0 = wp[0], w1 = wp[1];
      acc[0] += xq[q] * w0.x; acc[1] += xq[q] * w0.y; acc[2] += xq[q] * w0.z; acc[3] += xq[q] * w0.w;
      acc[4] += xq[q] * w1.x; acc[5] += xq[q] * w1.y; acc[6] += xq[q] * w1.z; acc[7] += xq[q] * w1.w;
    }
  }
#pragma unroll
  for (int off = 32; off; off >>= 1)
#pragma unroll
    for (int e = 0; e < 8; ++e) acc[e] += __shfl_xor(acc[e], off, 64);
  if (lane == 0) {
    float l[8], p[8];
    float m = -1e30f;
#pragma unroll
    for (int e = 0; e < 8; ++e) { l[e] = acc[e] + br[e]; m = fmaxf(m, l[e]); }
    float s = 0.f;
#pragma unroll
    for (int e = 0; e < 8; ++e) { p[e] = __expf(l[e] - m); s += p[e]; }
    int i1 = 0;
#pragma unroll
    for (int e = 1; e < 8; ++e) if (p[e] > p[i1]) i1 = e;   // ties -> lower idx
    int i2 = (i1 == 0) ? 1 : 0;
#pragma unroll
    for (int e = 0; e < 8; ++e) if (e != i1 && p[e] > p[i2]) i2 = e;
    float ps = p[i1] + p[i2];
    eidx[t * 2]     = i1;  ew[t * 2]     = p[i1] / ps;
    eidx[t * 2 + 1] = i2;  ew[t * 2 + 1] = p[i2] / ps;
  }
}

// ---------------- router pass 2: per-expert stream compaction (v2) ---------
// 8 blocks x 1024 threads. int4/float4 loads; 4 ballots per 4096-index
// chunk in slot order j=0..3; 4 chunks total (barriers 48 -> 12).
// List order is a fixed deterministic permutation -> output-invariant.

__global__ __launch_bounds__(1024) void build_lists_kernel(
    const int4* __restrict__ eidx4, const float4* __restrict__ ew4,
    int* __restrict__ counts, int* __restrict__ tok2, float* __restrict__ wl) {
  int e = blockIdx.x;
  int tid = threadIdx.x;
  int lane = tid & 63, wv = tid >> 6;    // 16 waves
  __shared__ int wsum[16];
  __shared__ int base;
  if (tid == 0) base = 0;
  __syncthreads();
#pragma unroll
  for (int c = 0; c < 4; ++c) {          // 4 chunks x 4096 indices
    int v4 = c * 1024 + tid;
    int4   ev = eidx4[v4];
    float4 fw = ew4[v4];
    bool m0 = (ev.x == e), m1 = (ev.y == e), m2 = (ev.z == e), m3 = (ev.w == e);
    unsigned long long b0 = __ballot(m0);
    unsigned long long b1 = __ballot(m1);
    unsigned long long b2 = __ballot(m2);
    unsigned long long b3 = __ballot(m3);
    int c0 = __popcll(b0), c1 = __popcll(b1), c2 = __popcll(b2), c3 = __popcll(b3);
    if (lane == 0) wsum[wv] = c0 + c1 + c2 + c3;
    __syncthreads();                     // wsum visible
    int wbase = base;
    for (int w = 0; w < wv; ++w) wbase += wsum[w];
    unsigned long long lm = (lane == 63) ? ~0ull >> 1 : (1ull << lane) - 1ull;
    lm = (1ull << lane) - 1ull;          // lanes below me
    int ibase = c * 4096 + tid * 4;
    int off0 = wbase;
    int off1 = off0 + c0;
    int off2 = off1 + c1;
    int off3 = off2 + c2;
    if (m0) { int p = off0 + __popcll(b0 & lm); tok2[e * TOKENS + p] = ibase + 0; wl[e * TOKENS + p] = fw.x; }
    if (m1) { int p = off1 + __popcll(b1 & lm); tok2[e * TOKENS + p] = ibase + 1; wl[e * TOKENS + p] = fw.y; }
    if (m2) { int p = off2 + __popcll(b2 & lm); tok2[e * TOKENS + p] = ibase + 2; wl[e * TOKENS + p] = fw.z; }
    if (m3) { int p = off3 + __popcll(b3 & lm); tok2[e * TOKENS + p] = ibase + 3; wl[e * TOKENS + p] = fw.w; }
    int total = 0;
#pragma unroll
    for (int w = 0; w < 16; ++w) total += wsum[w];
    __syncthreads();                     // all reads of base done
    if (tid == 0) base += total;
    __syncthreads();                     // base update visible
  }
  if (tid == 0) counts[e] = base;
}

// ---------------- gathered expert GEMM + gelu*gate epilogue ----------------
// R5-exact: C-tile 128x128, BK=32, 3-buffer counted-vmcnt, 4 waves 2x2,
// XCD swizzle (one expert per XCD), token-layout outslot writes.

__global__ __launch_bounds__(256, 3) void expert_gemm_kernel(
    const unsigned short* __restrict__ xb, const unsigned short* __restrict__ weT,
    const float* __restrict__ b_experts, const int* __restrict__ counts,
    const int* __restrict__ tok2, const float* __restrict__ wlist,
    unsigned short* __restrict__ outslot) {
  int b = blockIdx.x;
  int id = (b >> 3) + (b & 7) * 512;      // XCD k <- expert k's 512 tiles
  int e = id >> 9;
  int rem = id & 511;
  int m0 = (rem >> 3) << 7;               // 64 m-tiles, n fastest
  int n0 = (rem & 7) << 7;
  int cnt = counts[e];
  if (m0 >= cnt) return;

  __shared__ unsigned short As[3][128 * 32];   // [m][k]
  __shared__ unsigned short Bs[3][128 * 32];   // [n][k]
  __shared__ int   tokS[128];
  __shared__ float wS[128];

  int tid = threadIdx.x;
  if (tid < 128) {
    int r = m0 + tid;
    tokS[tid] = (r < cnt) ? tok2[e * TOKENS + r] : 0;
    wS[tid]   = (r < cnt) ? wlist[e * TOKENS + r] : 0.f;
  }
  __syncthreads();

  int wave = tid >> 6, lane = tid & 63;
  int subr = lane >> 2, koff = (lane & 3) * 8;

  const unsigned short* wbase = weT + (size_t)e * (HDIM * DDIM);
  const unsigned short* asrc[2];
  const unsigned short* bsrc[2];
  unsigned short* adst[3][2];
  unsigned short* bdst[3][2];
#pragma unroll
  for (int i = 0; i < 2; ++i) {
    int row = i * 64 + wave * 16 + subr;
    asrc[i] = xb + (size_t)(tokS[row] >> 1) * HDIM + koff;
    bsrc[i] = wbase + (size_t)(n0 + row) * HDIM + koff;
#pragma unroll
    for (int bb = 0; bb < 3; ++bb) {
      adst[bb][i] = &As[bb][i * 2048 + wave * 512];
      bdst[bb][i] = &Bs[bb][i * 2048 + wave * 512];
    }
  }

  int wm = wave & 1, wn = wave >> 1;
  int quad = lane >> 4, lr = lane & 15;

  f32x4 zero = {0.f, 0.f, 0.f, 0.f};
  f32x4 acc[4][4];
#pragma unroll
  for (int i = 0; i < 4; ++i)
#pragma unroll
    for (int j = 0; j < 4; ++j) acc[i][j] = zero;

  // prologue: stage k-steps 0,1 into buffers 0,1 (8 loads/thread in flight)
#pragma unroll
  for (int s = 0; s < 2; ++s)
#pragma unroll
    for (int i = 0; i < 2; ++i) {
      gld_lds16(asrc[i] + s * 32, adst[s][i]);
      gld_lds16(bsrc[i] + s * 32, bdst[s][i]);
    }

#pragma unroll
  for (int kk = 0; kk < 32; ++kk) {
    // wait for the 4 loads filling buffer kk%3; leave the next 4 in flight
    if (kk < 31) asm volatile("s_waitcnt vmcnt(4)" ::: "memory");
    else         asm volatile("s_waitcnt vmcnt(0)" ::: "memory");
    __builtin_amdgcn_s_barrier();        // buf kk%3 valid; buf (kk+2)%3 reads done
    if (kk + 2 < 32) {                   // stage k-step kk+2 into buffer (kk+2)%3
      int nb = (kk + 2) % 3;
      int off = (kk + 2) * 32;
#pragma unroll
      for (int i = 0; i < 2; ++i) {
        gld_lds16(asrc[i] + off, adst[nb][i]);
        gld_lds16(bsrc[i] + off, bdst[nb][i]);
      }
    }
    int cb = kk % 3;
    bf16x8 af[4], bfr[4];
#pragma unroll
    for (int i = 0; i < 4; ++i)
      af[i] = *(const bf16x8*)&As[cb][(wm * 64 + i * 16 + lr) * 32 + quad * 8];
#pragma unroll
    for (int j = 0; j < 4; ++j)
      bfr[j] = *(const bf16x8*)&Bs[cb][(wn * 64 + j * 16 + lr) * 32 + quad * 8];
#pragma unroll
    for (int i = 0; i < 4; ++i)
#pragma unroll
      for (int j = 0; j < 4; ++j)
        acc[i][j] = __builtin_amdgcn_mfma_f32_16x16x32_bf16(af[i], bfr[j], acc[i][j], 0, 0, 0);
  }

#pragma unroll
  for (int j = 0; j < 4; ++j) {
    int col = n0 + wn * 64 + j * 16 + lr;
    float bias = b_experts[e * DDIM + col];
#pragma unroll
    for (int i = 0; i < 4; ++i) {
      int rbase = wm * 64 + i * 16 + quad * 4;
#pragma unroll
      for (int r = 0; r < 4; ++r) {
        int row = rbase + r;
        if (m0 + row < cnt) {
          float h = acc[i][j][r] + bias;
          float z = 0.7978845608f * (h + 0.044715f * h * h * h);
          float t = 1.f - 2.f / (__expf(2.f * z) + 1.f);   // tanh(z), saturates safely
          float g = 0.5f * h * (1.f + t);
          outslot[(size_t)tokS[row] * DDIM + col] = f2b(g * wS[row]);
        }
      }
    }
  }
}

// ---------------- combine the two slots -> bf16 combined ----------------

__global__ void combine_kernel(const ushort4* __restrict__ outslot, ushort4* __restrict__ comb) {
  int i = blockIdx.x * 256 + threadIdx.x;  // TOKENS*DDIM/4 threads
  int t = i >> 8, d4 = i & 255;
  ushort4 a = outslot[t * 512 + d4];
  ushort4 b = outslot[t * 512 + 256 + d4];
  ushort4 o;
  o.x = f2b(b2f(a.x) + b2f(b.x));
  o.y = f2b(b2f(a.y) + b2f(b.y));
  o.z = f2b(b2f(a.z) + b2f(b.z));
  o.w = f2b(b2f(a.w) + b2f(b.w));
  comb[i] = o;
}

// ---------------- output projection GEMM (fp32 out) ----------------
// 128x128, 3-buffer counted-vmcnt pipeline, XCD swizzle (n-slab per XCD).

__global__ __launch_bounds__(256, 3) void out_gemm_kernel(
    const unsigned short* __restrict__ Abf, const unsigned short* __restrict__ BT,
    const float* __restrict__ bias, float* __restrict__ out) {
  int b = blockIdx.x;
  int id = (b >> 3) + (b & 7) * 64;       // XCD k <- n-tile k's 64 m-tiles
  int n0 = (id >> 6) << 7;
  int m0 = (id & 63) << 7;

  __shared__ unsigned short As[3][128 * 32];
  __shared__ unsigned short Bs[3][128 * 32];
  int tid = threadIdx.x, wave = tid >> 6, lane = tid & 63;
  int subr = lane >> 2, koff = (lane & 3) * 8;

  const unsigned short* asrc[2];
  const unsigned short* bsrc[2];
  unsigned short* adst[3][2];
  unsigned short* bdst[3][2];
#pragma unroll
  for (int i = 0; i < 2; ++i) {
    int row = i * 64 + wave * 16 + subr;
    asrc[i] = Abf + (size_t)(m0 + row) * DDIM + koff;
    bsrc[i] = BT + (size_t)(n0 + row) * DDIM + koff;
#pragma unroll
    for (int bb = 0; bb < 3; ++bb) {
      adst[bb][i] = &As[bb][i * 2048 + wave * 512];
      bdst[bb][i] = &Bs[bb][i * 2048 + wave * 512];
    }
  }

  int wm = wave & 1, wn = wave >> 1;
  int quad = lane >> 4, lr = lane & 15;

  f32x4 zero = {0.f, 0.f, 0.f, 0.f};
  f32x4 acc[4][4];
#pragma unroll
  for (int i = 0; i < 4; ++i)
#pragma unroll
    for (int j = 0; j < 4; ++j) acc[i][j] = zero;

#pragma unroll
  for (int s = 0; s < 2; ++s)
#pragma unroll
    for (int i = 0; i < 2; ++i) {
      gld_lds16(asrc[i] + s * 32, adst[s][i]);
      gld_lds16(bsrc[i] + s * 32, bdst[s][i]);
    }

#pragma unroll
  for (int kk = 0; kk < 32; ++kk) {
    if (kk < 31) asm volatile("s_waitcnt vmcnt(4)" ::: "memory");
    else         asm volatile("s_waitcnt vmcnt(0)" ::: "memory");
    __builtin_amdgcn_s_barrier();
    if (kk + 2 < 32) {
      int nb = (kk + 2) % 3;
      int off = (kk + 2) * 32;
#pragma unroll
      for (int i = 0; i < 2; ++i) {
        gld_lds16(asrc[i] + off, adst[nb][i]);
        gld_lds16(bsrc[i] + off, bdst[nb][i]);
      }
    }
    int cb = kk % 3;
    bf16x8 af[4], bfr[4];
#pragma unroll
    for (int i = 0; i < 4; ++i)
      af[i] = *(const bf16x8*)&As[cb][(wm * 64 + i * 16 + lr) * 32 + quad * 8];
#pragma unroll
    for (int j = 0; j < 4; ++j)
      bfr[j] = *(const bf16x8*)&Bs[cb][(wn * 64 + j * 16 + lr) * 32 + quad * 8];
#pragma unroll
    for (int i = 0; i < 4; ++i)
#pragma unroll
      for (int j = 0; j < 4; ++j)
        acc[i][j] = __builtin_amdgcn_mfma_f32_16x16x32_bf16(af[i], bfr[j], acc[i][j], 0, 0, 0);
  }

#pragma unroll
  for (int j = 0; j < 4; ++j) {
    int col = n0 + wn * 64 + j * 16 + lr;
    float bs = bias[col];
#pragma unroll
    for (int i = 0; i < 4; ++i) {
      int rbase = wm * 64 + i * 16 + quad * 4;
#pragma unroll
      for (int r = 0; r < 4; ++r)
        out[(size_t)(m0 + rbase + r) * DDIM + col] = acc[i][j][r] + bs;
    }
  }
}

// ---------------- launch ----------------

extern "C" void kernel_launch(void* const* d_in, const int* in_sizes, int n_in,
                              void* d_out, int out_size, void* d_ws, size_t ws_size,
                              hipStream_t stream) {
  const float* x  = (const float*)d_in[0];
  const float* wr = (const float*)d_in[1];
  const float* br = (const float*)d_in[2];
  const float* we = (const float*)d_in[3];
  const float* be = (const float*)d_in[4];
  const float* wo = (const float*)d_in[5];
  const float* bo = (const float*)d_in[6];
  float* out = (float*)d_out;

  char* ws = (char*)d_ws;
  unsigned short* xb      = (unsigned short*)(ws);                  // 16 MB
  unsigned short* weT     = (unsigned short*)(ws + 16777216);       // 16 MB
  unsigned short* woT     = (unsigned short*)(ws + 33554432);       //  2 MB
  unsigned short* outslot = (unsigned short*)(ws + 35651584);       // 32 MB
  int*            counts  = (int*)           (ws + 69206016);       // 256 B
  int*            tok2    = (int*)           (ws + 69206272);       // 256 KB
  float*          wlist   = (float*)         (ws + 69468416);       // 256 KB
  int*            eidx    = (int*)           (ws + 69730560);       // 64 KB
  float*          ew      = (float*)         (ws + 69796096);       // 64 KB
  unsigned short* comb    = xb;   // alias: xb dead after expert_gemm

  pre_kernel<<<2048 + 9216, 256, 0, stream>>>(x, wr, br, we, wo, weT, woT,
                                              xb, eidx, ew);
  build_lists_kernel<<<8, 1024, 0, stream>>>((const int4*)eidx, (const float4*)ew,
                                             counts, tok2, wlist);
  expert_gemm_kernel<<<4096, 256, 0, stream>>>(xb, weT, be, counts, tok2, wlist, outslot);
  combine_kernel<<<8192, 256, 0, stream>>>((const ushort4*)outslot, (ushort4*)comb);
  out_gemm_kernel<<<512, 256, 0, stream>>>(comb, woT, bo, out);
}